// Round 9
// baseline (119.388 us; speedup 1.0000x reference)
//
#include <hip/hip_runtime.h>
#include <hip/hip_bf16.h>
#include <math.h>

// VariableSelectionNetwork — MI355X (gfx950), round 9
//
// Identity 1: scorer LayerNorm over a size-1 axis => output == sc_ln_b =>
// softmax weights are constant; scorer GRN is dead code.
// Identity 2: gate logit = h1 @ (gate_w@fc2_w)^T + (gate_w@fc2_b + gate_b),
// so FC2+GATE fuse into one phase consuming h1. r7 proved the main-side
// works; its GF prep was a serial-latency blunder — now GF is a parallel
// MFMA GEMM (256 waves, 1 tile each).
//
// Round 9 structure: 4-wave/256-thr blocks (512-VGPR headroom), T=32,
// swizzled bf16 weights, TWO heavy GEMM phases, and cross-phase B-prefetch:
// next phase's B-loads are issued before the current barrier so the
// mandatory vmcnt(0) barrier-drain covers loads that already flew during
// compute (r8 showed lockstep waves can't hide latency any other way).

typedef __bf16 bf16;
typedef __bf16 bf16x8 __attribute__((ext_vector_type(8)));
typedef __bf16 bf16x4 __attribute__((ext_vector_type(4)));
typedef float f32x4 __attribute__((ext_vector_type(4)));

#define NTOK 8192
#define D_   256
#define F_   32

// ws layout (bytes)
#define OFF_C      512       // 256 f32: c[d]
#define OFF_BP     1536      // 256 f32: b' = gate_w@fc2_b + gate_b
#define OFF_WPROJT 4096      // WT[n][f] bf16, 16 KB
#define OFF_FC1    32768     // swizzled bf16, 128 KB each
#define OFF_FC2    163840
#define OFF_GF     294912    // swizzled bf16: GF = gate_w @ fc2_w

// Swizzled: elem = j*4096 + ks*512 + lm*32 + lq*8 + e
//   == W[row = j*16+lm][col = ks*32+lq*8+e]; wave (j,ks) load = 1 KB contig.

// prep grid: 0..15 swizzle fc1/fc2 | 16 softmax/WT/c | 17..80 GF tiles | 81..84 b'
__global__ __launch_bounds__(256) void vsn_prep(
    const float* __restrict__ proj_w, const float* __restrict__ proj_b,
    const float* __restrict__ sc_ln_b,
    const float* __restrict__ fc1w, const float* __restrict__ fc2w,
    const float* __restrict__ fc2b,
    const float* __restrict__ gatew, const float* __restrict__ gateb,
    float* __restrict__ wsC, float* __restrict__ wsBp, bf16* __restrict__ wsWT,
    bf16* __restrict__ oFC1, bf16* __restrict__ oFC2, bf16* __restrict__ oGF)
{
  const int blk = blockIdx.x;
  const int tid = threadIdx.x;
  if (blk < 16) {
    // fc1/fc2 -> swizzled bf16
    int g = blk * 256 + tid;                  // 0..4095
    int m = g >> 11;                          // 0=fc1, 1=fc2
    int c = g & 2047;
    const float* src = (m == 0) ? fc1w : fc2w;
    bf16* dst = (m == 0) ? oFC1 : oFC2;
    int row = c >> 3, ks = c & 7;
    int j = row >> 4, lmr = row & 15;
    const float* sp = src + row * 256 + ks * 32;
    bf16* dp = dst + j * 4096 + ks * 512 + lmr * 32;
    #pragma unroll
    for (int q = 0; q < 4; q++) {
      float4 a = ((const float4*)sp)[2 * q];
      float4 b = ((const float4*)sp)[2 * q + 1];
      bf16x8 v = {(bf16)a.x, (bf16)a.y, (bf16)a.z, (bf16)a.w,
                  (bf16)b.x, (bf16)b.y, (bf16)b.z, (bf16)b.w};
      *(bf16x8*)(dp + q * 8) = v;
    }
  } else if (blk == 16) {
    // softmax(sc_ln_b) -> WT row d + c[d]
    const int d = tid;
    float wv[F_];
    float mx = -3.0e38f;
    #pragma unroll
    for (int f = 0; f < F_; f++) { wv[f] = sc_ln_b[f]; mx = fmaxf(mx, wv[f]); }
    float se = 0.0f;
    #pragma unroll
    for (int f = 0; f < F_; f++) { wv[f] = __expf(wv[f] - mx); se += wv[f]; }
    float inv = 1.0f / se;
    float acc = 0.0f;
    #pragma unroll
    for (int f = 0; f < F_; f++) {
      float wf = wv[f] * inv;
      acc += wf * proj_b[f * D_ + d];
      wsWT[d * F_ + f] = (bf16)(wf * proj_w[f * D_ + d]);
    }
    wsC[d] = acc;
  } else if (blk < 81) {
    // GF = gate_w @ fc2_w via MFMA: one 16x16 tile per wave, K=256.
    const int w    = tid >> 6;
    const int lane = tid & 63;
    const int lm   = lane & 15;
    const int lq   = lane >> 4;
    const int id   = (blk - 17) * 4 + w;      // 0..255
    const int tm   = id >> 4, tn = id & 15;
    f32x4 acc = {0.f, 0.f, 0.f, 0.f};
    #pragma unroll
    for (int kb = 0; kb < 8; kb++) {
      // A[m][k]: gate_w row tm*16+lm, k = kb*32+lq*8+e (contig 32B)
      const float* ap = gatew + (size_t)(tm * 16 + lm) * 256 + kb * 32 + lq * 8;
      float4 a0 = *(const float4*)ap;
      float4 a1 = *(const float4*)(ap + 4);
      bf16x8 av = {(bf16)a0.x, (bf16)a0.y, (bf16)a0.z, (bf16)a0.w,
                   (bf16)a1.x, (bf16)a1.y, (bf16)a1.z, (bf16)a1.w};
      // B[k][n]: fc2_w[kb*32+lq*8+j][tn*16+lm] (strided gather, all indep)
      bf16x8 bv;
      #pragma unroll
      for (int j = 0; j < 8; j++)
        bv[j] = (bf16)fc2w[(size_t)(kb * 32 + lq * 8 + j) * 256 + tn * 16 + lm];
      acc = __builtin_amdgcn_mfma_f32_16x16x32_bf16(av, bv, acc, 0, 0, 0);
    }
    // store to swizzled layout: row=tm*16+lq*4+r, col=tn*16+lm
    bf16* dp = oGF + tm * 4096 + (tn >> 1) * 512 + (tn & 1) * 16 + lm;
    #pragma unroll
    for (int r = 0; r < 4; r++)
      dp[(lq * 4 + r) * 32] = (bf16)acc[r];
  } else {
    // b'[d] = gate_b[d] + sum_e gate_w[d][e]*fc2_b[e]; 64 rows per block
    __shared__ float sB[256];
    __shared__ float sRed[64][4];
    sB[tid] = fc2b[tid];
    __syncthreads();
    const int row = (blk - 81) * 64 + (tid >> 2);
    const int ch  = tid & 3;                  // 64-float chunk
    const float4* gp = (const float4*)(gatew + (size_t)row * 256 + ch * 64);
    float p = 0.0f;
    #pragma unroll
    for (int q = 0; q < 16; q++) {
      float4 g = gp[q];
      int e = ch * 64 + q * 4;
      p += g.x * sB[e] + g.y * sB[e + 1] + g.z * sB[e + 2] + g.w * sB[e + 3];
    }
    sRed[tid >> 2][ch] = p;
    __syncthreads();
    if (ch == 0)
      wsBp[row] = gateb[row] + sRed[tid >> 2][0] + sRed[tid >> 2][1] +
                  sRed[tid >> 2][2] + sRed[tid >> 2][3];
  }
}

// ---- main: 32 tokens / 4-wave block; wave w owns cols [64w, 64w+64) ----
__global__ __launch_bounds__(256, 1) void vsn_main(
    const float* __restrict__ x,
    const float* __restrict__ wsC,
    const bf16* __restrict__ WT,
    const bf16* __restrict__ FC1, const float* __restrict__ fc1_b,
    const bf16* __restrict__ FC2, const float* __restrict__ fc2_b,
    const bf16* __restrict__ GF, const float* __restrict__ bprime,
    const float* __restrict__ ln_g, const float* __restrict__ ln_b,
    float* __restrict__ out)
{
  __shared__ bf16  sAct[2][32][264];
  __shared__ float sLN[4][32][2];

  const int tid  = threadIdx.x;
  const int w    = tid >> 6;
  const int lane = tid & 63;
  const int lm   = lane & 15;
  const int lq   = lane >> 4;
  const int j0   = w * 4;
  const int tok0 = blockIdx.x * 32;

  // ---------- hoisted loads: everything scalar/small issues up front ----------
  int nn[4];
  float cv[4], b1v[4], b2v[4], bpv[4], lgv[4], lbv[4];
  #pragma unroll
  for (int jj = 0; jj < 4; jj++) {
    nn[jj]  = (j0 + jj) * 16 + lm;
    cv[jj]  = wsC[nn[jj]];
    b1v[jj] = fc1_b[nn[jj]];
    b2v[jj] = fc2_b[nn[jj]];
    bpv[jj] = bprime[nn[jj]];
    lgv[jj] = ln_g[nn[jj]];
    lbv[jj] = ln_b[nn[jj]];
  }
  bf16x8 aX[2];
  #pragma unroll
  for (int t = 0; t < 2; t++) {
    const float* xp = x + (size_t)(tok0 + t * 16 + lm) * F_ + lq * 8;
    float4 x0 = *(const float4*)xp;
    float4 x1 = *(const float4*)(xp + 4);
    bf16x8 av = {(bf16)x0.x, (bf16)x0.y, (bf16)x0.z, (bf16)x0.w,
                 (bf16)x1.x, (bf16)x1.y, (bf16)x1.z, (bf16)x1.w};
    aX[t] = av;
  }
  bf16x8 bWT[4];
  #pragma unroll
  for (int jj = 0; jj < 4; jj++)
    bWT[jj] = *(const bf16x8*)(WT + nn[jj] * F_ + lq * 8);

  // prefetch phase-2 jj0 (flies during phase 1)
  const bf16* f1base = FC1 + j0 * 4096 + lm * 32 + lq * 8;
  bf16x8 b0[8], b1[8], b2[8], b3[8];
  #pragma unroll
  for (int ks = 0; ks < 8; ks++)
    b0[ks] = *(const bf16x8*)(f1base + ks * 512);

  // ---------- phase 1: mix = x @ WT^T + c ----------
  f32x4 mixf[2][4];
  #pragma unroll
  for (int jj = 0; jj < 4; jj++) {
    #pragma unroll
    for (int t = 0; t < 2; t++) {
      f32x4 acc = {cv[jj], cv[jj], cv[jj], cv[jj]};
      acc = __builtin_amdgcn_mfma_f32_16x16x32_bf16(aX[t], bWT[jj], acc, 0, 0, 0);
      mixf[t][jj] = acc;
      bf16x4 mh = {(bf16)acc[0], (bf16)acc[1], (bf16)acc[2], (bf16)acc[3]};
      #pragma unroll
      for (int r = 0; r < 4; r++) sAct[0][t * 16 + lq * 4 + r][nn[jj]] = mh[r];
    }
  }
  __syncthreads();

  // ---------- phase 2: h1 = elu(mix @ fc1^T + b1), explicit jj pipeline ----------
  bf16x8 af[2][8];
  #pragma unroll
  for (int t = 0; t < 2; t++)
    #pragma unroll
    for (int ks = 0; ks < 8; ks++)
      af[t][ks] = *(const bf16x8*)(&sAct[0][t * 16 + lm][ks * 32 + lq * 8]);

  const bf16* f2base = FC2 + j0 * 4096 + lm * 32 + lq * 8;
  const bf16* gfbase = GF  + j0 * 4096 + lm * 32 + lq * 8;
  bf16x8 cF[8], cG[8];   // phase-3 jj0 prefetch

  auto ph2_mfma = [&](const bf16x8* bb, int jj) {
    f32x4 a0 = {0.f, 0.f, 0.f, 0.f}, a1 = {0.f, 0.f, 0.f, 0.f};
    #pragma unroll
    for (int ks = 0; ks < 8; ks++) {
      a0 = __builtin_amdgcn_mfma_f32_16x16x32_bf16(af[0][ks], bb[ks], a0, 0, 0, 0);
      a1 = __builtin_amdgcn_mfma_f32_16x16x32_bf16(af[1][ks], bb[ks], a1, 0, 0, 0);
    }
    #pragma unroll
    for (int r = 0; r < 4; r++) {
      float v0 = a0[r] + b1v[jj];
      v0 = (v0 > 0.0f) ? v0 : (__expf(v0) - 1.0f);
      sAct[1][lq * 4 + r][nn[jj]] = (bf16)v0;
      float v1 = a1[r] + b1v[jj];
      v1 = (v1 > 0.0f) ? v1 : (__expf(v1) - 1.0f);
      sAct[1][16 + lq * 4 + r][nn[jj]] = (bf16)v1;
    }
  };

  #pragma unroll
  for (int ks = 0; ks < 8; ks++) b1[ks] = *(const bf16x8*)(f1base + 4096 + ks * 512);
  ph2_mfma(b0, 0);
  #pragma unroll
  for (int ks = 0; ks < 8; ks++) b2[ks] = *(const bf16x8*)(f1base + 8192 + ks * 512);
  ph2_mfma(b1, 1);
  #pragma unroll
  for (int ks = 0; ks < 8; ks++) b3[ks] = *(const bf16x8*)(f1base + 12288 + ks * 512);
  #pragma unroll
  for (int ks = 0; ks < 8; ks++) {        // phase-3 jj0 prefetch, flies across barrier
    cF[ks] = *(const bf16x8*)(f2base + ks * 512);
    cG[ks] = *(const bf16x8*)(gfbase + ks * 512);
  }
  ph2_mfma(b2, 2);
  ph2_mfma(b3, 3);
  __syncthreads();

  // ---------- phase 3 (fused FC2+GATE): y2 in registers ----------
  #pragma unroll
  for (int t = 0; t < 2; t++)
    #pragma unroll
    for (int ks = 0; ks < 8; ks++)
      af[t][ks] = *(const bf16x8*)(&sAct[1][t * 16 + lm][ks * 32 + lq * 8]);

  f32x4 y2[2][4];
  bf16x8 dF[8], dG[8];
  auto ph3_step = [&](const bf16x8* bF, const bf16x8* bG, int jj) {
    f32x4 hF0 = {0.f,0.f,0.f,0.f}, hF1 = {0.f,0.f,0.f,0.f};
    f32x4 hG0 = {0.f,0.f,0.f,0.f}, hG1 = {0.f,0.f,0.f,0.f};
    #pragma unroll
    for (int ks = 0; ks < 8; ks++) {
      hF0 = __builtin_amdgcn_mfma_f32_16x16x32_bf16(af[0][ks], bF[ks], hF0, 0, 0, 0);
      hF1 = __builtin_amdgcn_mfma_f32_16x16x32_bf16(af[1][ks], bF[ks], hF1, 0, 0, 0);
      hG0 = __builtin_amdgcn_mfma_f32_16x16x32_bf16(af[0][ks], bG[ks], hG0, 0, 0, 0);
      hG1 = __builtin_amdgcn_mfma_f32_16x16x32_bf16(af[1][ks], bG[ks], hG1, 0, 0, 0);
    }
    #pragma unroll
    for (int r = 0; r < 4; r++) {
      float h20 = hF0[r] + b2v[jj];
      float g0  = 1.0f / (1.0f + __expf(-(hG0[r] + bpv[jj])));
      y2[0][jj][r] = g0 * h20 + (1.0f - g0) * mixf[0][jj][r];
      float h21 = hF1[r] + b2v[jj];
      float g1  = 1.0f / (1.0f + __expf(-(hG1[r] + bpv[jj])));
      y2[1][jj][r] = g1 * h21 + (1.0f - g1) * mixf[1][jj][r];
    }
  };

  #pragma unroll
  for (int ks = 0; ks < 8; ks++) {
    dF[ks] = *(const bf16x8*)(f2base + 4096 + ks * 512);
    dG[ks] = *(const bf16x8*)(gfbase + 4096 + ks * 512);
  }
  ph3_step(cF, cG, 0);
  #pragma unroll
  for (int ks = 0; ks < 8; ks++) {
    cF[ks] = *(const bf16x8*)(f2base + 8192 + ks * 512);
    cG[ks] = *(const bf16x8*)(gfbase + 8192 + ks * 512);
  }
  ph3_step(dF, dG, 1);
  #pragma unroll
  for (int ks = 0; ks < 8; ks++) {
    dF[ks] = *(const bf16x8*)(f2base + 12288 + ks * 512);
    dG[ks] = *(const bf16x8*)(gfbase + 12288 + ks * 512);
  }
  ph3_step(cF, cG, 2);
  ph3_step(dF, dG, 3);

  // ---------- LayerNorm(256) via cross-wave partial sums ----------
  #pragma unroll
  for (int t = 0; t < 2; t++) {
    float rs[4] = {0.f,0.f,0.f,0.f}, rq[4] = {0.f,0.f,0.f,0.f};
    #pragma unroll
    for (int jj = 0; jj < 4; jj++)
      #pragma unroll
      for (int r = 0; r < 4; r++) {
        float y = y2[t][jj][r];
        rs[r] += y;
        rq[r] += y * y;
      }
    #pragma unroll
    for (int r = 0; r < 4; r++) {
      #pragma unroll
      for (int off = 1; off < 16; off <<= 1) {
        rs[r] += __shfl_xor(rs[r], off);
        rq[r] += __shfl_xor(rq[r], off);
      }
      if (lm == 0) {
        sLN[w][t * 16 + lq * 4 + r][0] = rs[r];
        sLN[w][t * 16 + lq * 4 + r][1] = rq[r];
      }
    }
  }
  __syncthreads();

  const float inv_d = 1.0f / 256.0f;
  #pragma unroll
  for (int t = 0; t < 2; t++) {
    float mean[4], rstd[4];
    #pragma unroll
    for (int r = 0; r < 4; r++) {
      int row = t * 16 + lq * 4 + r;
      float S = sLN[0][row][0] + sLN[1][row][0] + sLN[2][row][0] + sLN[3][row][0];
      float Q = sLN[0][row][1] + sLN[1][row][1] + sLN[2][row][1] + sLN[3][row][1];
      float m = S * inv_d;
      mean[r] = m;
      rstd[r] = rsqrtf(Q * inv_d - m * m + 1e-5f);
    }
    #pragma unroll
    for (int jj = 0; jj < 4; jj++) {
      #pragma unroll
      for (int r = 0; r < 4; r++) {
        float o = (y2[t][jj][r] - mean[r]) * rstd[r] * lgv[jj] + lbv[jj];
        out[(size_t)(tok0 + t * 16 + lq * 4 + r) * D_ + nn[jj]] = o;
      }
    }
  }
}

extern "C" void kernel_launch(void* const* d_in, const int* in_sizes, int n_in,
                              void* d_out, int out_size, void* d_ws, size_t ws_size,
                              hipStream_t stream) {
  (void)in_sizes; (void)n_in; (void)ws_size; (void)out_size;
  const float* x      = (const float*)d_in[0];
  const float* proj_w = (const float*)d_in[1];
  const float* proj_b = (const float*)d_in[2];
  const float* sclnb  = (const float*)d_in[12];
  const float* fc1w   = (const float*)d_in[13];
  const float* fc1b   = (const float*)d_in[14];
  const float* fc2w   = (const float*)d_in[15];
  const float* fc2b   = (const float*)d_in[16];
  const float* gw     = (const float*)d_in[17];
  const float* gb     = (const float*)d_in[18];
  const float* lng    = (const float*)d_in[19];
  const float* lnb    = (const float*)d_in[20];

  char* ws = (char*)d_ws;
  float* wsC  = (float*)(ws + OFF_C);
  float* wsBp = (float*)(ws + OFF_BP);
  bf16*  wsWT = (bf16*)(ws + OFF_WPROJT);
  bf16*  bFC1 = (bf16*)(ws + OFF_FC1);
  bf16*  bFC2 = (bf16*)(ws + OFF_FC2);
  bf16*  bGF  = (bf16*)(ws + OFF_GF);

  vsn_prep<<<85, 256, 0, stream>>>(proj_w, proj_b, sclnb, fc1w, fc2w, fc2b,
                                   gw, gb, wsC, wsBp, wsWT, bFC1, bFC2, bGF);
  vsn_main<<<NTOK / 32, 256, 0, stream>>>(x, wsC, wsWT,
                                          bFC1, fc1b, bFC2, fc2b, bGF, wsBp,
                                          lng, lnb, (float*)d_out);
}

// Round 10
// 112.363 us; speedup vs baseline: 1.0625x; 1.0625x over previous
//
#include <hip/hip_runtime.h>
#include <hip/hip_bf16.h>
#include <math.h>

// VariableSelectionNetwork — MI355X (gfx950), round 10
//
// Identity: scorer LayerNorm over a size-1 axis => output == sc_ln_b, so
// softmax weights W[f] = softmax(sc_ln_b) are constant and the scorer GRN is
// dead code. Remaining: mix = x @ WT^T + c ; post-GRN (3x 256x256) ; gated
// skip ; LayerNorm(256).
//
// Round 10 = EXACT round-5 main (best measured: 113.4 µs total; every
// structural variant since — smaller tiles r6, gate-fusion r7, 8-wave r8,
// barrier-crossing prefetch r9 — measured neutral or worse) + widened prep
// (48 swizzle blocks, 16-elem chunks: 2 loads/thread instead of 8).

typedef __bf16 bf16;
typedef __bf16 bf16x8 __attribute__((ext_vector_type(8)));
typedef __bf16 bf16x4 __attribute__((ext_vector_type(4)));
typedef float f32x4 __attribute__((ext_vector_type(4)));

#define NTOK 8192
#define D_   256
#define F_   32

// ws layout (bytes)
#define OFF_C      512       // 256 f32
#define OFF_WPROJT 2048      // WT[n][f] bf16 (fragment-coalesced), 16 KB
#define OFF_FC1    32768     // swizzled bf16, 128 KB each
#define OFF_FC2    163840
#define OFF_GATE   294912

// Swizzled layout: elem = j*4096 + ks*512 + lm*32 + lq*8 + e
//   == W[row = j*16+lm][col = ks*32 + lq*8 + e]; a wave's (j,ks) fragment
// load is one contiguous 1 KB segment.

// ---- prep: blocks 0..47 swizzle-convert 3 weights; block 48 softmax/WT/c ----
__global__ __launch_bounds__(256) void vsn_prep(
    const float* __restrict__ proj_w, const float* __restrict__ proj_b,
    const float* __restrict__ sc_ln_b,
    const float* __restrict__ w1, const float* __restrict__ w2,
    const float* __restrict__ w3,
    float* __restrict__ wsC, bf16* __restrict__ wsWT,
    bf16* __restrict__ o1, bf16* __restrict__ o2, bf16* __restrict__ o3)
{
  const int blk = blockIdx.x;
  if (blk < 48) {
    int g = blk * 256 + threadIdx.x;          // 0..12287 half-chunks (16 floats)
    int m = g >> 12;                          // matrix 0..2
    int c = g & 4095;                         // row = c>>4, ks = (c>>1)&7, half = c&1
    const float* src = (m == 0) ? w1 : (m == 1) ? w2 : w3;
    bf16* dst = (m == 0) ? o1 : (m == 1) ? o2 : o3;
    int row = c >> 4, ks = (c >> 1) & 7, half = c & 1;
    int j = row >> 4, lmr = row & 15;
    const float* sp = src + row * 256 + ks * 32 + half * 16;  // 16 contig floats
    bf16* dp = dst + j * 4096 + ks * 512 + lmr * 32 + half * 16;
    #pragma unroll
    for (int q = 0; q < 2; q++) {
      float4 a = ((const float4*)sp)[2 * q];
      float4 b = ((const float4*)sp)[2 * q + 1];
      bf16x8 v = {(bf16)a.x, (bf16)a.y, (bf16)a.z, (bf16)a.w,
                  (bf16)b.x, (bf16)b.y, (bf16)b.z, (bf16)b.w};
      *(bf16x8*)(dp + q * 8) = v;
    }
  } else {
    const int d = threadIdx.x;
    float wv[F_];
    float mx = -3.0e38f;
    #pragma unroll
    for (int f = 0; f < F_; f++) { wv[f] = sc_ln_b[f]; mx = fmaxf(mx, wv[f]); }
    float se = 0.0f;
    #pragma unroll
    for (int f = 0; f < F_; f++) { wv[f] = __expf(wv[f] - mx); se += wv[f]; }
    float inv = 1.0f / se;
    float acc = 0.0f;
    #pragma unroll
    for (int f = 0; f < F_; f++) {
      float wf = wv[f] * inv;
      acc += wf * proj_b[f * D_ + d];
      wsWT[d * F_ + f] = (bf16)(wf * proj_w[f * D_ + d]);
    }
    wsC[d] = acc;
  }
}

// ---- main: 32 tokens / 4-wave block; wave w owns cols [64w, 64w+64) ----
__global__ __launch_bounds__(256, 1) void vsn_main(
    const float* __restrict__ x,
    const float* __restrict__ wsC,
    const bf16* __restrict__ WT,
    const bf16* __restrict__ FC1, const float* __restrict__ fc1_b,
    const bf16* __restrict__ FC2, const float* __restrict__ fc2_b,
    const bf16* __restrict__ GATE, const float* __restrict__ gate_b,
    const float* __restrict__ ln_g, const float* __restrict__ ln_b,
    float* __restrict__ out)
{
  __shared__ bf16  sAct[2][32][264];   // ping-pong bf16 activations (A operand)
  __shared__ float sY[32][260];        // fp32 y2 for LayerNorm

  const int tid  = threadIdx.x;
  const int w    = tid >> 6;
  const int lane = tid & 63;
  const int lm   = lane & 15;
  const int lq   = lane >> 4;
  const int j0   = w * 4;
  const int tok0 = blockIdx.x * 32;

  // ---- phase 1: mix = x @ WT^T + c (K=32); 2 M-tiles share each B ----
  bf16x4 mixh[2][4];
  {
    bf16x8 a[2];
    #pragma unroll
    for (int t = 0; t < 2; t++) {
      const float* xp = x + (size_t)(tok0 + t * 16 + lm) * F_ + lq * 8;
      float4 x0 = *(const float4*)xp;
      float4 x1 = *(const float4*)(xp + 4);
      bf16x8 av = {(bf16)x0.x, (bf16)x0.y, (bf16)x0.z, (bf16)x0.w,
                   (bf16)x1.x, (bf16)x1.y, (bf16)x1.z, (bf16)x1.w};
      a[t] = av;
    }
    #pragma unroll
    for (int jj = 0; jj < 4; jj++) {
      int n = (j0 + jj) * 16 + lm;
      bf16x8 b = *(const bf16x8*)(WT + n * F_ + lq * 8);   // 1KB/wave contig
      float cv = wsC[n];
      #pragma unroll
      for (int t = 0; t < 2; t++) {
        f32x4 acc = {cv, cv, cv, cv};
        acc = __builtin_amdgcn_mfma_f32_16x16x32_bf16(a[t], b, acc, 0, 0, 0);
        bf16x4 mh = {(bf16)acc[0], (bf16)acc[1], (bf16)acc[2], (bf16)acc[3]};
        mixh[t][jj] = mh;
        #pragma unroll
        for (int r = 0; r < 4; r++) sAct[0][t * 16 + lq * 4 + r][n] = mh[r];
      }
    }
  }
  __syncthreads();

  // generic phase: read A-tiles from sAct[src], gemm vs swizzled W, epilogue
  auto gemmPhase = [&](int src, const bf16* __restrict__ W, auto&& epi) {
    bf16x8 af[2][8];
    #pragma unroll
    for (int t = 0; t < 2; t++)
      #pragma unroll
      for (int ks = 0; ks < 8; ks++)
        af[t][ks] = *(const bf16x8*)(&sAct[src][t * 16 + lm][ks * 32 + lq * 8]);
    const bf16* base = W + j0 * 4096 + lm * 32 + lq * 8;
    bf16x8 bb[8];
    #pragma unroll
    for (int ks = 0; ks < 8; ks++)
      bb[ks] = *(const bf16x8*)(base + ks * 512);          // 1KB/wave contig
    #pragma unroll
    for (int jj = 0; jj < 4; jj++) {
      bf16x8 bn[8];
      if (jj < 3) {
        const bf16* nb = base + (jj + 1) * 4096;
        #pragma unroll
        for (int ks = 0; ks < 8; ks++)
          bn[ks] = *(const bf16x8*)(nb + ks * 512);
      }
      f32x4 acc0 = {0.f, 0.f, 0.f, 0.f}, acc1 = {0.f, 0.f, 0.f, 0.f};
      #pragma unroll
      for (int ks = 0; ks < 8; ks++) {
        acc0 = __builtin_amdgcn_mfma_f32_16x16x32_bf16(af[0][ks], bb[ks], acc0, 0, 0, 0);
        acc1 = __builtin_amdgcn_mfma_f32_16x16x32_bf16(af[1][ks], bb[ks], acc1, 0, 0, 0);
      }
      epi(jj, acc0, acc1);
      if (jj < 3) {
        #pragma unroll
        for (int ks = 0; ks < 8; ks++) bb[ks] = bn[ks];
      }
    }
  };

  // ---- phase 2: h1 = elu(mix @ fc1^T + b1) -> sAct[1] ----
  gemmPhase(0, FC1, [&](int jj, f32x4& a0, f32x4& a1) {
    int n = (j0 + jj) * 16 + lm;
    float bias = fc1_b[n];
    #pragma unroll
    for (int r = 0; r < 4; r++) {
      float v0 = a0[r] + bias;
      v0 = (v0 > 0.0f) ? v0 : (__expf(v0) - 1.0f);
      sAct[1][lq * 4 + r][n] = (bf16)v0;
      float v1 = a1[r] + bias;
      v1 = (v1 > 0.0f) ? v1 : (__expf(v1) - 1.0f);
      sAct[1][16 + lq * 4 + r][n] = (bf16)v1;
    }
  });
  __syncthreads();

  // ---- phase 3: h2 = h1 @ fc2^T + b2 -> sAct[0], keep packed regs ----
  bf16x4 h2h[2][4];
  gemmPhase(1, FC2, [&](int jj, f32x4& a0, f32x4& a1) {
    int n = (j0 + jj) * 16 + lm;
    float bias = fc2_b[n];
    bf16x4 h0, h1v;
    #pragma unroll
    for (int r = 0; r < 4; r++) {
      h0[r]  = (bf16)(a0[r] + bias);
      h1v[r] = (bf16)(a1[r] + bias);
      sAct[0][lq * 4 + r][n] = h0[r];
      sAct[0][16 + lq * 4 + r][n] = h1v[r];
    }
    h2h[0][jj] = h0;
    h2h[1][jj] = h1v;
  });
  __syncthreads();

  // ---- phase 4: gate, gated skip -> sY ----
  gemmPhase(0, GATE, [&](int jj, f32x4& a0, f32x4& a1) {
    int n = (j0 + jj) * 16 + lm;
    float bias = gate_b[n];
    #pragma unroll
    for (int r = 0; r < 4; r++) {
      float s0 = a0[r] + bias;
      float g0 = 1.0f / (1.0f + __expf(-s0));
      sY[lq * 4 + r][n] = g0 * (float)h2h[0][jj][r] + (1.0f - g0) * (float)mixh[0][jj][r];
      float s1 = a1[r] + bias;
      float g1 = 1.0f / (1.0f + __expf(-s1));
      sY[16 + lq * 4 + r][n] = g1 * (float)h2h[1][jj][r] + (1.0f - g1) * (float)mixh[1][jj][r];
    }
  });
  __syncthreads();

  // ---- phase 5: LayerNorm(256); 16-lane group handles 2 tokens ----
  const float inv_d = 1.0f / 256.0f;
  #pragma unroll
  for (int rep = 0; rep < 2; rep++) {
    const int t = (w * 4 + lq) * 2 + rep;
    float4 yv[4];
    #pragma unroll
    for (int i = 0; i < 4; i++)
      yv[i] = *(const float4*)(&sY[t][lm * 4 + i * 64]);
    float s = 0.0f;
    #pragma unroll
    for (int i = 0; i < 4; i++) s += yv[i].x + yv[i].y + yv[i].z + yv[i].w;
    #pragma unroll
    for (int off = 1; off < 16; off <<= 1) s += __shfl_xor(s, off);
    float mean = s * inv_d;
    float q = 0.0f;
    #pragma unroll
    for (int i = 0; i < 4; i++) {
      float d0 = yv[i].x - mean, d1 = yv[i].y - mean,
            d2 = yv[i].z - mean, d3 = yv[i].w - mean;
      q += d0 * d0 + d1 * d1 + d2 * d2 + d3 * d3;
    }
    #pragma unroll
    for (int off = 1; off < 16; off <<= 1) q += __shfl_xor(q, off);
    float rstd = rsqrtf(q * inv_d + 1e-5f);
    #pragma unroll
    for (int i = 0; i < 4; i++) {
      int n = lm * 4 + i * 64;
      float4 gv = *(const float4*)(ln_g + n);
      float4 bv = *(const float4*)(ln_b + n);
      float4 o;
      o.x = (yv[i].x - mean) * rstd * gv.x + bv.x;
      o.y = (yv[i].y - mean) * rstd * gv.y + bv.y;
      o.z = (yv[i].z - mean) * rstd * gv.z + bv.z;
      o.w = (yv[i].w - mean) * rstd * gv.w + bv.w;
      *(float4*)(out + (size_t)(tok0 + t) * D_ + n) = o;
    }
  }
}

extern "C" void kernel_launch(void* const* d_in, const int* in_sizes, int n_in,
                              void* d_out, int out_size, void* d_ws, size_t ws_size,
                              hipStream_t stream) {
  (void)in_sizes; (void)n_in; (void)ws_size; (void)out_size;
  const float* x      = (const float*)d_in[0];
  const float* proj_w = (const float*)d_in[1];
  const float* proj_b = (const float*)d_in[2];
  const float* sclnb  = (const float*)d_in[12];
  const float* fc1w   = (const float*)d_in[13];
  const float* fc1b   = (const float*)d_in[14];
  const float* fc2w   = (const float*)d_in[15];
  const float* fc2b   = (const float*)d_in[16];
  const float* gw     = (const float*)d_in[17];
  const float* gb     = (const float*)d_in[18];
  const float* lng    = (const float*)d_in[19];
  const float* lnb    = (const float*)d_in[20];

  char* ws = (char*)d_ws;
  float* wsC   = (float*)(ws + OFF_C);
  bf16*  wsWT  = (bf16*)(ws + OFF_WPROJT);
  bf16*  bFC1  = (bf16*)(ws + OFF_FC1);
  bf16*  bFC2  = (bf16*)(ws + OFF_FC2);
  bf16*  bGATE = (bf16*)(ws + OFF_GATE);

  vsn_prep<<<49, 256, 0, stream>>>(proj_w, proj_b, sclnb, fc1w, fc2w, gw,
                                   wsC, wsWT, bFC1, bFC2, bGATE);
  vsn_main<<<NTOK / 32, 256, 0, stream>>>(x, wsC, wsWT,
                                          bFC1, fc1b, bFC2, fc2b, bGATE, gb,
                                          lng, lnb, (float*)d_out);
}